// Round 1
// baseline (419.382 us; speedup 1.0000x reference)
//
#include <hip/hip_runtime.h>

// GumbelSlotSelector via MFMA: layer1 (524288x64x128 fp32 GEMM) done as
// 6-term exact 3xbf16-split MFMA. Layer2 + gumbel + ballot fixup fused in a
// per-wave epilogue. This revision targets load duty-cycle:
//  - ks-loop software-pipelined with 1-deep register prefetch (incl. cross-tile)
//  - first tile's loads issued before the W1 preamble (preamble hides latency)
//  - per-tile __syncthreads removed: the red[] transpose is wave-private, and
//    LDS ops within a wave are in-order -> wave_barrier (compile fence) only.
//  - grid 256 x 4 tiles: exactly 1 resident block/CU, waves free-run.

typedef __attribute__((ext_vector_type(8))) short bf16x8;
typedef __attribute__((ext_vector_type(4))) float f32x4;

constexpr int NROWS = 8192 * 64;   // 524288
constexpr int D = 128, H = 64;

__device__ __forceinline__ void split3(float x, unsigned& h1, unsigned& h2, unsigned& h3) {
    unsigned ux = __float_as_uint(x);
    h1 = ux & 0xFFFF0000u;                       // top 8 mantissa bits
    float r = x - __uint_as_float(h1);           // exact
    h2 = __float_as_uint(r) & 0xFFFF0000u;       // next 8
    float r2 = r - __uint_as_float(h2);          // exact
    h3 = __float_as_uint(r2) & 0xFFFF0000u;      // remaining bits (exact)
}

__global__ __launch_bounds__(512, 2)
void gumbel_slot_mfma(const float* __restrict__ slots,
                      const float* __restrict__ gumbel_u,
                      const float* __restrict__ fix_u,
                      const float* __restrict__ W1,
                      const float* __restrict__ b1,
                      const float* __restrict__ W2,
                      const float* __restrict__ b2,
                      float* __restrict__ out)
{
    // LDS: W1 3-split bf16, j-major [split][j=64][d=128], 16B chunks XOR-swizzled
    // by (j&15); plus wave-private epilogue transpose scratch. Total 64 KB.
    __shared__ __align__(16) unsigned short wt[3 * 64 * 128];  // 48 KB
    __shared__ __align__(16) float red[8][16][16][2];          // 16 KB

    const int tid  = threadIdx.x;
    const int wv   = tid >> 6;        // wave 0..7
    const int lane = tid & 63;
    const int quad = lane >> 4;       // 0..3
    const int col  = lane & 15;       // 0..15

    const int tile0 = blockIdx.x * 4;               // 4 consecutive tiles/block
    const int row0  = tile0 * 512 + wv * 64;        // wave's rows in tile 0

    // ---- issue tile0/ks0 loads FIRST: W1 preamble below hides the latency ----
    float4 f[4][2];
#pragma unroll
    for (int mt = 0; mt < 4; ++mt) {
        const float* arow = slots + (size_t)(row0 + mt * 16 + col) * D + quad * 8;
        f[mt][0] = *(const float4*)arow;
        f[mt][1] = *(const float4*)(arow + 4);
    }

    // ---- one-time: split W1 into 3 bf16 planes, transposed [j][d] ----
#pragma unroll
    for (int i = 0; i < 16; ++i) {
        const int e = i * 512 + tid;          // 8192 elements, coalesced
        const int d = e >> 6, j = e & 63;
        unsigned h1, h2, h3;
        split3(W1[e], h1, h2, h3);
        const int chunk = (d >> 3) ^ (j & 15);           // 16B-chunk swizzle
        const int idx = j * 128 + chunk * 8 + (d & 7);
        wt[idx]             = (unsigned short)(h1 >> 16);
        wt[idx + 8192]      = (unsigned short)(h2 >> 16);
        wt[idx + 16384]     = (unsigned short)(h3 >> 16);
    }
    __syncthreads();   // wt is cross-wave shared: this barrier stays

    // per-lane constants (same for all tiles)
    float  b1v[4];
    float2 w2v[4];
#pragma unroll
    for (int nt = 0; nt < 4; ++nt) {
        b1v[nt] = b1[nt * 16 + col];
        w2v[nt] = *(const float2*)(W2 + (size_t)(nt * 16 + col) * 2);
    }
    const float2 b2v = *(const float2*)b2;

#pragma unroll 1
    for (int t = 0; t < 4; ++t) {
        const int tile = tile0 + t;
        const int rowW = tile * 512 + wv * 64;           // this wave's 64 rows
        const int r    = rowW + lane;

        // prefetch epilogue operand early (consumed ~4 ks-steps later)
        const float2 gu = *(const float2*)(gumbel_u + (size_t)r * 2);

        f32x4 acc[4][4];
#pragma unroll
        for (int mt = 0; mt < 4; ++mt)
#pragma unroll
            for (int nt = 0; nt < 4; ++nt)
                acc[mt][nt] = f32x4{b1v[nt], b1v[nt], b1v[nt], b1v[nt]};

#pragma unroll
        for (int ks = 0; ks < 4; ++ks) {                 // k0 = ks*32
            // ---- prefetch next k-chunk (or next tile's first chunk) ----
            float4 fn[4][2];                             // dead-garbage only at (t==3,ks==3)
            if (ks < 3) {
#pragma unroll
                for (int mt = 0; mt < 4; ++mt) {
                    const float* arow = slots + (size_t)(rowW + mt * 16 + col) * D
                                              + (ks + 1) * 32 + quad * 8;
                    fn[mt][0] = *(const float4*)arow;
                    fn[mt][1] = *(const float4*)(arow + 4);
                }
            } else if (t < 3) {
#pragma unroll
                for (int mt = 0; mt < 4; ++mt) {
                    const float* arow = slots + (size_t)(rowW + 512 + mt * 16 + col) * D
                                              + quad * 8;
                    fn[mt][0] = *(const float4*)arow;
                    fn[mt][1] = *(const float4*)(arow + 4);
                }
            }

            // ---- convert current chunk (loaded one step ago) to A-fragments ----
            bf16x8 a1[4], a2[4], a3[4];
#pragma unroll
            for (int mt = 0; mt < 4; ++mt) {
                const float xs[8] = {f[mt][0].x, f[mt][0].y, f[mt][0].z, f[mt][0].w,
                                     f[mt][1].x, f[mt][1].y, f[mt][1].z, f[mt][1].w};
                union { int i[4]; bf16x8 v; } u1, u2, u3;
#pragma unroll
                for (int p = 0; p < 4; ++p) {
                    unsigned xh1, xh2, xh3, yh1, yh2, yh3;
                    split3(xs[2 * p],     xh1, xh2, xh3);
                    split3(xs[2 * p + 1], yh1, yh2, yh3);
                    u1.i[p] = (int)((xh1 >> 16) | yh1);  // [k even | k odd]
                    u2.i[p] = (int)((xh2 >> 16) | yh2);
                    u3.i[p] = (int)((xh3 >> 16) | yh3);
                }
                a1[mt] = u1.v; a2[mt] = u2.v; a3[mt] = u3.v;
            }

#pragma unroll
            for (int nt = 0; nt < 4; ++nt) {
                const int j = nt * 16 + col;
                const int chunk = (ks * 4 + quad) ^ col;
                const unsigned short* wp = &wt[j * 128 + chunk * 8];
                const bf16x8 bq1 = *(const bf16x8*)(wp);
                const bf16x8 bq2 = *(const bf16x8*)(wp + 8192);
                const bf16x8 bq3 = *(const bf16x8*)(wp + 16384);
#pragma unroll
                for (int mt = 0; mt < 4; ++mt) {
                    f32x4 c = acc[mt][nt];
                    c = __builtin_amdgcn_mfma_f32_16x16x32_bf16(a1[mt], bq1, c, 0, 0, 0);
                    c = __builtin_amdgcn_mfma_f32_16x16x32_bf16(a2[mt], bq1, c, 0, 0, 0);
                    c = __builtin_amdgcn_mfma_f32_16x16x32_bf16(a1[mt], bq2, c, 0, 0, 0);
                    c = __builtin_amdgcn_mfma_f32_16x16x32_bf16(a2[mt], bq2, c, 0, 0, 0);
                    c = __builtin_amdgcn_mfma_f32_16x16x32_bf16(a1[mt], bq3, c, 0, 0, 0);
                    c = __builtin_amdgcn_mfma_f32_16x16x32_bf16(a3[mt], bq1, c, 0, 0, 0);
                    acc[mt][nt] = c;
                }
            }

            // rotate prefetch buffer (register-renamed away by full unroll)
#pragma unroll
            for (int mt = 0; mt < 4; ++mt) { f[mt][0] = fn[mt][0]; f[mt][1] = fn[mt][1]; }
        }

        // ---- epilogue: layer2 partials + per-row transpose via LDS ----
        // red[wv] is WAVE-PRIVATE; LDS ops within a wave are in-order, so no
        // block barrier is needed — only a compiler code-motion fence.
        // C layout: col(n=j) = lane&15, row = mt*16 + quad*4 + reg.
        float fl0 = 0.f, fl1 = 0.f;
#pragma unroll 1
        for (int mt = 0; mt < 4; ++mt) {
#pragma unroll
            for (int reg = 0; reg < 4; ++reg) {
                float p0 = 0.f, p1 = 0.f;
#pragma unroll
                for (int nt = 0; nt < 4; ++nt) {
                    const float h = fmaxf(acc[mt][nt][reg], 0.f);
                    p0 = fmaf(h, w2v[nt].x, p0);
                    p1 = fmaf(h, w2v[nt].y, p1);
                }
                const int rl = quad * 4 + reg;
                *(float2*)&red[wv][rl][col ^ rl][0] = make_float2(p0, p1);
            }
            __builtin_amdgcn_wave_barrier();
            if (quad == mt) {
                const int rl = col;           // local row within this mt
                float s0 = 0.f, s1 = 0.f;
#pragma unroll
                for (int c = 0; c < 16; ++c) {
                    const float2 v = *(const float2*)&red[wv][rl][c ^ rl][0];
                    s0 += v.x; s1 += v.y;
                }
                fl0 = s0; fl1 = s1;
            }
            __builtin_amdgcn_wave_barrier();
        }
        const float l0 = fl0 + b2v.x;
        const float l1 = fl1 + b2v.y;

        // ---- gumbel decision + keep prob ----
        const float lo = 1e-10f, hi = (float)(1.0 - 1e-7);
        const float u0 = fminf(fmaxf(gu.x, lo), hi);
        const float u1 = fminf(fmaxf(gu.y, lo), hi);
        const float g0 = -logf(-logf(u0));
        const float g1 = -logf(-logf(u1));
        float dec = ((l1 + g1) > (l0 + g0)) ? 1.0f : 0.0f;

        const float m  = fmaxf(l0, l1);
        const float e0 = expf(l0 - m), e1 = expf(l1 - m);
        const float keep = e1 / (e0 + e1);

        // ensure-minimum: this wave's 64 lanes == one b's 64 slots
        const unsigned long long act = __ballot(dec != 0.0f);
        if (act == 0ull) {
            float v = fix_u[r];
            int  idx = lane;
#pragma unroll
            for (int off = 32; off > 0; off >>= 1) {
                const float ov  = __shfl_xor(v, off, 64);
                const int  oidx = __shfl_xor(idx, off, 64);
                if (ov > v || (ov == v && oidx < idx)) { v = ov; idx = oidx; }
            }
            if (lane == idx) dec = 1.0f;
        }

        out[r] = dec;
        out[NROWS + r] = keep;
    }
}

extern "C" void kernel_launch(void* const* d_in, const int* in_sizes, int n_in,
                              void* d_out, int out_size, void* d_ws, size_t ws_size,
                              hipStream_t stream)
{
    const float* slots  = (const float*)d_in[0];
    const float* gumbel = (const float*)d_in[1];
    const float* fixu   = (const float*)d_in[2];
    const float* W1     = (const float*)d_in[3];
    const float* b1     = (const float*)d_in[4];
    const float* W2     = (const float*)d_in[5];
    const float* b2     = (const float*)d_in[6];
    float* out = (float*)d_out;

    gumbel_slot_mfma<<<256, 512, 0, stream>>>(
        slots, gumbel, fixu, W1, b1, W2, b2, out);
}